// Round 4
// baseline (111.479 us; speedup 1.0000x reference)
//
#include <hip/hip_runtime.h>

// DynFilter3D: out[b,h,w,o] = sum_{i,j,t} x[b,t,h+i-1,w+j-1] * f[b,h,w,(i*9+j*3+t),o]
// x: (B=8, T=3, H=192, W=192) f32   f: (B,H,W,27,16) f32   out: (B,H,W,16) f32
// Memory-bound: f (509.6 MB) streamed exactly once (~84.5us floor at 6.3 TB/s).
// f loads + out stores are NONTEMPORAL (stream past L2, no write-allocate);
// x halo staged in LDS per 64-pixel row segment.
// NOTE: __builtin_nontemporal_* requires a clang ext_vector type, not HIP float4.

typedef float f32x4 __attribute__((ext_vector_type(4)));

#define B_ 8
#define T_ 3
#define H_ 192
#define W_ 192
#define CO_ 16
#define KT_ 27          // 3*3*3 taps
#define PIX_PER_BLK 64  // one row segment; W = 3 * 64
#define XS_N (3 * 3 * 66)  // [t][i][ww'] halo tile

__global__ __launch_bounds__(256) void DynFilter3D_kernel(
    const float* __restrict__ x,
    const float* __restrict__ f,
    float* __restrict__ out)
{
    // block -> (b, h, wt); 64 pixels at w0 = wt*64, 4 threads/pixel
    int blk = blockIdx.x;
    int wt  = blk % 3;
    int bh  = blk / 3;
    int h   = bh % H_;
    int b   = bh / H_;
    int w0  = wt * PIX_PER_BLK;

    __shared__ float xs[XS_N];  // [t][i][66], ww' = w - w0 + 1

    // ---- stage x halo: 594 floats, coalesced, 3 rounds of 256 threads ----
    for (int idx = threadIdx.x; idx < XS_N; idx += 256) {
        int wwp = idx % 66;
        int ti  = idx / 66;      // t*3 + i
        int i   = ti % 3;
        int t   = ti / 3;
        int hh  = h + i - 1;
        int ww  = w0 + wwp - 1;
        float v = 0.0f;
        if ((unsigned)hh < (unsigned)H_ && (unsigned)ww < (unsigned)W_)
            v = x[(size_t)((b * T_ + t) * H_ + hh) * W_ + ww];
        xs[idx] = v;
    }
    __syncthreads();

    int wl = threadIdx.x >> 2;   // local pixel 0..63
    int t4 = threadIdx.x & 3;    // which float4 of 16 channels

    // ---- patches from LDS (broadcast reads, no vmcnt traffic) ----
    float patches[KT_];
#pragma unroll
    for (int i = 0; i < 3; ++i)
#pragma unroll
        for (int j = 0; j < 3; ++j)
#pragma unroll
            for (int t = 0; t < 3; ++t)
                patches[(i * 3 + j) * 3 + t] = xs[(t * 3 + i) * 66 + wl + j];

    // ---- stream this pixel's f block: 27 x float4, nontemporal ----
    size_t pix = (size_t)(b * H_ + h) * W_ + w0 + wl;
    const f32x4* fb = reinterpret_cast<const f32x4*>(f + pix * (KT_ * CO_));
    f32x4 acc = (f32x4)(0.0f);
#pragma unroll
    for (int k = 0; k < KT_; ++k) {
        f32x4 fv = __builtin_nontemporal_load(fb + k * 4 + t4);
        float  p  = patches[k];
        acc.x = fmaf(p, fv.x, acc.x);
        acc.y = fmaf(p, fv.y, acc.y);
        acc.z = fmaf(p, fv.z, acc.z);
        acc.w = fmaf(p, fv.w, acc.w);
    }

    __builtin_nontemporal_store(acc, reinterpret_cast<f32x4*>(out + pix * CO_) + t4);
}

extern "C" void kernel_launch(void* const* d_in, const int* in_sizes, int n_in,
                              void* d_out, int out_size, void* d_ws, size_t ws_size,
                              hipStream_t stream) {
    const float* x = (const float*)d_in[0];   // 8*3*192*192
    const float* f = (const float*)d_in[1];   // 8*192*192*27*16
    float* out = (float*)d_out;               // 8*192*192*16

    const int grid = B_ * H_ * 3;             // 4608 blocks, 64 pixels each
    DynFilter3D_kernel<<<grid, 256, 0, stream>>>(x, f, out);
}

// Round 5
// 97.264 us; speedup vs baseline: 1.1461x; 1.1461x over previous
//
#include <hip/hip_runtime.h>

// DynFilter3D: out[b,h,w,o] = sum_{i,j,t} x[b,t,h+i-1,w+j-1] * f[b,h,w,(i*9+j*3+t),o]
// x: (B=8, T=3, H=192, W=192) f32   f: (B,H,W,27,16) f32   out: (B,H,W,16) f32
// Memory-bound: f (509.6 MB) streamed exactly once (~84.5us floor at 6.3 TB/s).
//
// Round-5 structure: 8 lanes per pixel. Lane j owns channel-quad (j&3) and
// tap-parity (j>>2); it loads float4 index e = j + 8m (m=0..13) of the pixel's
// 108-float4 f block -> every wave instruction reads one FULL 128B line per
// pixel-group (vs 64B half-lines before). Patches staged per-pixel in LDS.
// Tap-parity partial sums merged with one shfl_xor(4); lanes j<4 store.

#define B_ 8
#define T_ 3
#define H_ 192
#define W_ 192
#define CO_ 16
#define KT_ 27            // 3*3*3 taps
#define PIX_PER_BLK 32    // 256 threads / 8 lanes-per-pixel
#define HALO_W 34         // 32 + 2
#define XS_N (3 * 3 * HALO_W)      // 306 floats: [t][i][w']
#define PL_N (PIX_PER_BLK * KT_)   // 864 floats: [pixel][tap]

__global__ __launch_bounds__(256) void DynFilter3D_kernel(
    const float* __restrict__ x,
    const float* __restrict__ f,
    float* __restrict__ out)
{
    // block -> (b, h, wt); 32 pixels at w0 = wt*32
    int blk = blockIdx.x;
    int wt  = blk % 6;
    int bh  = blk / 6;
    int h   = bh % H_;
    int b   = bh / H_;
    int w0  = wt * PIX_PER_BLK;

    __shared__ float xs[XS_N];
    __shared__ float pl[PL_N];

    // ---- stage x halo: 306 floats, coalesced ----
    for (int idx = threadIdx.x; idx < XS_N; idx += 256) {
        int wp = idx % HALO_W;
        int ti = idx / HALO_W;   // t*3 + i
        int i  = ti % 3;
        int t  = ti / 3;
        int hh = h + i - 1;
        int ww = w0 + wp - 1;
        float v = 0.0f;
        if ((unsigned)hh < (unsigned)H_ && (unsigned)ww < (unsigned)W_)
            v = x[(size_t)((b * T_ + t) * H_ + hh) * W_ + ww];
        xs[idx] = v;
    }
    __syncthreads();

    // ---- expand to per-pixel patch table pl[pixel][k], k = (i*3+j)*3 + t ----
    for (int idx = threadIdx.x; idx < PL_N; idx += 256) {
        int k  = idx % KT_;
        int pxl = idx / KT_;
        int t  = k % 3;
        int ij = k / 3;          // i*3 + j
        int jw = ij % 3;
        int i  = ij / 3;
        pl[idx] = xs[(t * 3 + i) * HALO_W + pxl + jw];
    }
    __syncthreads();

    int wl = threadIdx.x >> 3;   // local pixel 0..31
    int j  = threadIdx.x & 7;    // lane within pixel group
    int k0 = j >> 2;             // tap parity owned by this lane
    size_t pix = (size_t)(b * H_ + h) * W_ + w0 + wl;

    const float4* fb = reinterpret_cast<const float4*>(f + pix * (KT_ * CO_));
    const float*  pp = pl + wl * KT_ + k0;

    float4 acc = make_float4(0.f, 0.f, 0.f, 0.f);
#pragma unroll
    for (int m = 0; m < 14; ++m) {
        int e = j + 8 * m;       // float4 index in [0,108): quad = j&3, tap = k0+2m
        if (e < KT_ * 4) {
            float4 fv = fb[e];
            float  p  = pp[2 * m];
            acc.x = fmaf(p, fv.x, acc.x);
            acc.y = fmaf(p, fv.y, acc.y);
            acc.z = fmaf(p, fv.z, acc.z);
            acc.w = fmaf(p, fv.w, acc.w);
        }
    }

    // merge the two tap-parities: lanes j and j^4 hold the same channel quad
    acc.x += __shfl_xor(acc.x, 4);
    acc.y += __shfl_xor(acc.y, 4);
    acc.z += __shfl_xor(acc.z, 4);
    acc.w += __shfl_xor(acc.w, 4);

    if (j < 4)
        reinterpret_cast<float4*>(out + pix * CO_)[j] = acc;
}

extern "C" void kernel_launch(void* const* d_in, const int* in_sizes, int n_in,
                              void* d_out, int out_size, void* d_ws, size_t ws_size,
                              hipStream_t stream) {
    const float* x = (const float*)d_in[0];   // 8*3*192*192
    const float* f = (const float*)d_in[1];   // 8*192*192*27*16
    float* out = (float*)d_out;               // 8*192*192*16

    const int grid = B_ * H_ * (W_ / PIX_PER_BLK);   // 9216 blocks
    DynFilter3D_kernel<<<grid, 256, 0, stream>>>(x, f, out);
}